// Round 12
// baseline (1703.463 us; speedup 1.0000x reference)
//
#include <hip/hip_runtime.h>

typedef short bfx8 __attribute__((ext_vector_type(8)));   // 8 bf16 (bit pattern)
typedef float f32x4 __attribute__((ext_vector_type(4)));
typedef unsigned short ushort_t;
typedef unsigned int uint_t;
typedef unsigned long long ull_t;

#define SIGN4 0x8000800080008000ull
#define MASK4 0x7fff7fff7fff7fffull

__device__ inline ushort_t f2bf(float x) {
    union { float f; uint_t u; } v; v.f = x;
    uint_t r = v.u + 0x7fffu + ((v.u >> 16) & 1u);   // RNE
    return (ushort_t)(r >> 16);
}
__device__ inline float bf2f(ushort_t b) {
    union { uint_t u; float f; } v; v.u = ((uint_t)b) << 16;
    return v.f;
}

// ---------------- fp32 -> bf16 conversion (vectorized) ----------------
__global__ void f2bf_kernel(const float* __restrict__ in, ushort_t* __restrict__ out, int n4) {
    int i = blockIdx.x * 256 + threadIdx.x;
    if (i < n4) {
        float4 v = ((const float4*)in)[i];
        ushort4 o;
        o.x = f2bf(v.x); o.y = f2bf(v.y); o.z = f2bf(v.z); o.w = f2bf(v.w);
        ((ushort4*)out)[i] = o;
    }
}

// bf16 trace -> fp32 hiddens (8 elems/thread)
__global__ void expand_kernel(const ushort_t* __restrict__ hb, float* __restrict__ out, int n8) {
    int i = blockIdx.x * 256 + threadIdx.x;
    if (i < n8) {
        bfx8 v = ((const bfx8*)hb)[i];
        float4 lo, hi;
        lo.x = bf2f((ushort_t)v[0]); lo.y = bf2f((ushort_t)v[1]);
        lo.z = bf2f((ushort_t)v[2]); lo.w = bf2f((ushort_t)v[3]);
        hi.x = bf2f((ushort_t)v[4]); hi.y = bf2f((ushort_t)v[5]);
        hi.z = bf2f((ushort_t)v[6]); hi.w = bf2f((ushort_t)v[7]);
        ((float4*)out)[2 * i] = lo;
        ((float4*)out)[2 * i + 1] = hi;
    }
}

// ring init: every bf16 sign bit = 1 (never matches first-use parity 0)
__global__ void init_ring(ull_t* __restrict__ p) {
    p[blockIdx.x * 256 + threadIdx.x] = SIGN4;
}

// ---------------- generic bf16 GEMM: C[M,N] = A[M,K] @ Bw[N,K]^T + bias ----------------
#define BM 128
#define BN 128
#define BKK 64
#define LDT 88

template<int RELU, int OUT_BF16, int HAS_B2>
__global__ __launch_bounds__(256)
void gemm_bt(const ushort_t* __restrict__ A, const ushort_t* __restrict__ Bw,
             const float* __restrict__ bias1, const float* __restrict__ bias2,
             float* __restrict__ Cf, ushort_t* __restrict__ Cb,
             int M, int N, int K)
{
    __shared__ ushort_t As[BM][LDT];
    __shared__ ushort_t Bs[BN][LDT];
    const int tid = threadIdx.x;
    const int l = tid & 63;
    const int wv = tid >> 6;
    const int wm = wv >> 1, wn = wv & 1;
    const int nbm = M / BM;
    const int im = blockIdx.x % nbm;
    const int in = blockIdx.x / nbm;
    const int m0 = im * BM, n0 = in * BN;

    f32x4 acc[4][4];
#pragma unroll
    for (int i = 0; i < 4; i++)
#pragma unroll
        for (int j = 0; j < 4; j++) acc[i][j] = {0.f, 0.f, 0.f, 0.f};

    for (int k0 = 0; k0 < K; k0 += BKK) {
#pragma unroll
        for (int i = 0; i < 4; ++i) {
            int c = i * 256 + tid;
            int row = c >> 3, cb = c & 7;
            *(bfx8*)&As[row][cb * 8] = *(const bfx8*)&A[(size_t)(m0 + row) * K + k0 + cb * 8];
        }
#pragma unroll
        for (int i = 0; i < 4; ++i) {
            int c = i * 256 + tid;
            int row = c >> 3, cb = c & 7;
            *(bfx8*)&Bs[row][cb * 8] = *(const bfx8*)&Bw[(size_t)(n0 + row) * K + k0 + cb * 8];
        }
        __syncthreads();
#pragma unroll
        for (int kk = 0; kk < 2; ++kk) {
            bfx8 av[4], bv[4];
#pragma unroll
            for (int i = 0; i < 4; i++)
                av[i] = *(const bfx8*)&As[wm * 64 + i * 16 + (l & 15)][kk * 32 + (l >> 4) * 8];
#pragma unroll
            for (int i = 0; i < 4; i++)
                bv[i] = *(const bfx8*)&Bs[wn * 64 + i * 16 + (l & 15)][kk * 32 + (l >> 4) * 8];
#pragma unroll
            for (int i = 0; i < 4; i++)
#pragma unroll
                for (int j = 0; j < 4; j++)
                    acc[i][j] = __builtin_amdgcn_mfma_f32_16x16x32_bf16(av[i], bv[j], acc[i][j], 0, 0, 0);
        }
        __syncthreads();
    }

#pragma unroll
    for (int j = 0; j < 4; j++) {
        int n = n0 + wn * 64 + j * 16 + (l & 15);
        float bi = bias1[n] + (HAS_B2 ? bias2[n] : 0.0f);
#pragma unroll
        for (int i = 0; i < 4; i++) {
            int mbase = m0 + wm * 64 + i * 16 + (l >> 4) * 4;
#pragma unroll
            for (int r = 0; r < 4; r++) {
                float v = acc[i][j][r] + bi;
                if (RELU) v = fmaxf(v, 0.0f);
                size_t idx = (size_t)(mbase + r) * N + n;
                if (OUT_BF16) Cb[idx] = f2bf(v);
                else          Cf[idx] = v;
            }
        }
    }
}

// ---------------- persistent recurrence kernel (parity tags, early poll issue) ---------
// 64 WGs = 4 batch-groups (16 rows) x 16 j-slices (64 cols). Exchange via 256 KB ring
// hx[2][64][1024] (slot = t&1); bf16 sign bits carry parity (t>>1)&1 (ReLU => true sign
// always 0). Producer packs directly from epilogue registers (4x 2B agent stores).
// Poll batch 1 issues BEFORE the Z prefetch, so round-1's compiler waitcnt is a counted
// vmcnt(4) (Z newer) instead of vmcnt(0) -> round 1 checks ~750cy post-pack and round 2
// ~1450cy, cutting the round-quantization penalty. Consumer-side coalesced trace store
// (R11-proven; no scattered sub-line HBM writes).
#define T_STEPS 512

#define STEP(t, zc, zn, rd, wr)                                                         \
    do {                                                                                \
        const ull_t pb4 = (((t) >> 1) & 1) ? SIGN4 : 0ull;                              \
        const ushort_t pbu = (((t) >> 1) & 1) ? (ushort_t)0x8000u : (ushort_t)0;        \
        f32x4 a0 = {0.f,0.f,0.f,0.f}, a1 = {0.f,0.f,0.f,0.f};                           \
        f32x4 a2 = {0.f,0.f,0.f,0.f}, a3 = {0.f,0.f,0.f,0.f};                           \
        if ((t) > 0) {                                                                  \
            _Pragma("unroll") for (int k0 = 0; k0 < 32; k0 += 4) {                      \
                bfx8 h0 = *(const bfx8*)&rd[l & 15][(k0 + 0) * 32 + (l >> 4) * 8];      \
                bfx8 h1 = *(const bfx8*)&rd[l & 15][(k0 + 1) * 32 + (l >> 4) * 8];      \
                bfx8 h2 = *(const bfx8*)&rd[l & 15][(k0 + 2) * 32 + (l >> 4) * 8];      \
                bfx8 h3 = *(const bfx8*)&rd[l & 15][(k0 + 3) * 32 + (l >> 4) * 8];      \
                a0 = __builtin_amdgcn_mfma_f32_16x16x32_bf16(h0, wreg[k0 + 0], a0, 0, 0, 0); \
                a1 = __builtin_amdgcn_mfma_f32_16x16x32_bf16(h1, wreg[k0 + 1], a1, 0, 0, 0); \
                a2 = __builtin_amdgcn_mfma_f32_16x16x32_bf16(h2, wreg[k0 + 2], a2, 0, 0, 0); \
                a3 = __builtin_amdgcn_mfma_f32_16x16x32_bf16(h3, wreg[k0 + 3], a3, 0, 0, 0); \
            }                                                                           \
        }                                                                               \
        f32x4 acc = (a0 + a1) + (a2 + a3);                                              \
        ushort_t hv[4];                                                                 \
        _Pragma("unroll") for (int r = 0; r < 4; r++) {                                 \
            int br = (l >> 4) * 4 + r;                                                  \
            hv[r] = f2bf(fmaxf(zc[r] + acc[r], 0.f));                                   \
            /* direct 2B pack from registers: fire-and-forget, agent scope */           \
            __hip_atomic_store(                                                         \
                &hx[(size_t)((t) & 1) * 65536 + (size_t)(b0 + br) * 1024 + jcol],       \
                (ushort_t)(hv[r] | pbu), __ATOMIC_RELAXED, __HIP_MEMORY_SCOPE_AGENT);   \
        }                                                                               \
        if ((t) + 1 < T_STEPS) {                                                        \
            /* poll batch 1 issues FIRST (round-1 check then waits only vmcnt(4)) */    \
            const ull_t* src = (const ull_t*)(hx + (size_t)((t) & 1) * 65536            \
                                              + (size_t)b0 * 1024);                     \
            ull_t sv[16];                                                               \
            _Pragma("unroll") for (int i2 = 0; i2 < 16; i2++)                           \
                sv[i2] = __hip_atomic_load(src + i2 * 256 + tid, __ATOMIC_RELAXED,      \
                                           __HIP_MEMORY_SCOPE_AGENT);                   \
            _Pragma("unroll") for (int r = 0; r < 4; r++) {   /* Z prefetch t+1 */      \
                int br = (l >> 4) * 4 + r;                                              \
                zn[r] = bf2f(__builtin_nontemporal_load(                                \
                    &Z[((size_t)((t) + 1) * 64 + b0 + br) * 1024 + jcol]));             \
            }                                                                           \
            __builtin_amdgcn_sched_barrier(0);                                          \
            uint_t okm = 1u;                                                            \
            _Pragma("unroll") for (int i2 = 0; i2 < 16; i2++)                           \
                okm &= (uint_t)((sv[i2] & SIGN4) == pb4);                               \
            while (!okm) {                                                              \
                _Pragma("unroll") for (int i2 = 0; i2 < 16; i2++)                       \
                    sv[i2] = __hip_atomic_load(src + i2 * 256 + tid, __ATOMIC_RELAXED,  \
                                               __HIP_MEMORY_SCOPE_AGENT);               \
                okm = 1u;                                                               \
                _Pragma("unroll") for (int i2 = 0; i2 < 16; i2++)                       \
                    okm &= (uint_t)((sv[i2] & SIGN4) == pb4);                           \
            }                                                                           \
            /* consumer-side coalesced trace: this WG owns row w (one 2KB block) */     \
            __builtin_nontemporal_store(sv[w] & MASK4,                                  \
                (ull_t*)(hbt + (size_t)(t) * 65536 + (size_t)b0 * 1024)                 \
                    + (size_t)w * 256 + tid);                                           \
            _Pragma("unroll") for (int i2 = 0; i2 < 16; i2++)                           \
                *(ull_t*)&wr[i2][tid * 4] = sv[i2] & MASK4;                             \
            asm volatile("s_waitcnt lgkmcnt(0)" ::: "memory");                          \
            __builtin_amdgcn_s_barrier();                                               \
            __builtin_amdgcn_sched_barrier(0);                                          \
        } else {                                                                        \
            /* final step: trace from registers (once; 2B nontemporal) */               \
            _Pragma("unroll") for (int r = 0; r < 4; r++) {                             \
                int br = (l >> 4) * 4 + r;                                              \
                __builtin_nontemporal_store(hv[r],                                      \
                    &hbt[(size_t)(t) * 65536 + (size_t)(b0 + br) * 1024 + jcol]);       \
            }                                                                           \
        }                                                                               \
    } while (0)

__global__ __launch_bounds__(256, 1)
void recurrence_kernel(const ushort_t* __restrict__ Z,     // [T*64,1024] bf16
                       const float* __restrict__ W_hh,     // [1024,1024] fp32
                       ushort_t* __restrict__ hbt,         // [T*64,1024] bf16 clean trace
                       ushort_t* __restrict__ hx)          // [2*64,1024] bf16 parity ring
{
    alignas(16) __shared__ ushort_t Hs0[16][1048];   // double-buffered group-h staging
    alignas(16) __shared__ ushort_t Hs1[16][1048];

    const int tid = threadIdx.x;
    const int l = tid & 63;
    const int v = tid >> 6;                // wave 0..3
    const int g = blockIdx.x >> 4;         // batch group 0..3
    const int w = blockIdx.x & 15;         // j-slice 0..15
    const int b0 = g * 16;
    const int jcol = w * 64 + v * 16 + (l & 15);

    // one-time: W_hh slice -> registers (fp32 -> bf16), 128 VGPRs
    bfx8 wreg[32];
#pragma unroll
    for (int k0 = 0; k0 < 32; k0++) {
        const float* p = &W_hh[(size_t)jcol * 1024 + k0 * 32 + (l >> 4) * 8];
        float4 f0 = *(const float4*)p;
        float4 f1 = *(const float4*)(p + 4);
        bfx8 t;
        t[0] = (short)f2bf(f0.x); t[1] = (short)f2bf(f0.y);
        t[2] = (short)f2bf(f0.z); t[3] = (short)f2bf(f0.w);
        t[4] = (short)f2bf(f1.x); t[5] = (short)f2bf(f1.y);
        t[6] = (short)f2bf(f1.z); t[7] = (short)f2bf(f1.w);
        wreg[k0] = t;
    }

    // Z for t=0
    float zfA[4], zfB[4];
#pragma unroll
    for (int r = 0; r < 4; r++) {
        int br = (l >> 4) * 4 + r;
        zfA[r] = bf2f(__builtin_nontemporal_load(&Z[(size_t)(b0 + br) * 1024 + jcol]));
    }

    for (int t2 = 0; t2 < T_STEPS; t2 += 2) {
        STEP(t2,     zfA, zfB, Hs0, Hs1);
        STEP(t2 + 1, zfB, zfA, Hs1, Hs0);
    }
}

extern "C" void kernel_launch(void* const* d_in, const int* in_sizes, int n_in,
                              void* d_out, int out_size, void* d_ws, size_t ws_size,
                              hipStream_t stream) {
    const float* in_sig = (const float*)d_in[0];   // [512,64,256]
    const float* W_in  = (const float*)d_in[2];    // [1024,256]
    const float* b_in  = (const float*)d_in[3];
    const float* W_ih  = (const float*)d_in[4];    // [1024,1024]
    const float* b_ih  = (const float*)d_in[5];
    const float* W_hh  = (const float*)d_in[6];    // [1024,1024]
    const float* b_hh  = (const float*)d_in[7];
    const float* W_out = (const float*)d_in[8];    // [256,1024]
    const float* b_out = (const float*)d_in[9];

    char* ws = (char*)d_ws;
    const size_t MB = 1ull << 20;
    ushort_t* inb   = (ushort_t*)(ws + 0);          // 16 MB  [0,16)
    ushort_t* Winb  = (ushort_t*)(ws + 17 * MB);    // 0.5 MB
    ushort_t* Wihb  = (ushort_t*)(ws + 18 * MB);    // 2 MB
    ushort_t* Xb    = (ushort_t*)(ws + 21 * MB);    // 64 MB  [21,85)
    ushort_t* hbt   = (ushort_t*)(ws + 0);          // 64 MB  alias [0,64) — dead by then
    ushort_t* Woutb = (ushort_t*)(ws + 85 * MB);    // 0.5 MB
    ushort_t* Zb    = (ushort_t*)(ws + 86 * MB);    // 64 MB  [86,150)
    ushort_t* hx    = (ushort_t*)(ws + 150 * MB);   // 256 KB parity ring

    float* hiddens = (float*)d_out;                      // [512,64,1024]
    float* outputs = (float*)d_out + 33554432;           // [512,64,256]

    f2bf_kernel<<<8192, 256, 0, stream>>>(in_sig, inb, 2097152);
    f2bf_kernel<<<256, 256, 0, stream>>>(W_in, Winb, 65536);
    f2bf_kernel<<<1024, 256, 0, stream>>>(W_ih, Wihb, 262144);
    f2bf_kernel<<<256, 256, 0, stream>>>(W_out, Woutb, 65536);

    // X = relu(In @ W_in^T + b_in)  [32768,1024] bf16
    gemm_bt<1, 1, 0><<<2048, 256, 0, stream>>>(inb, Winb, b_in, nullptr,
                                               nullptr, Xb, 32768, 1024, 256);
    // Z = X @ W_ih^T + b_ih + b_hh  [32768,1024] bf16
    gemm_bt<0, 1, 1><<<2048, 256, 0, stream>>>(Xb, Wihb, b_ih, b_hh,
                                               nullptr, Zb, 32768, 1024, 1024);

    // ring -> sign=1 (blocks first-step poll until real data; replay-safe)
    init_ring<<<128, 256, 0, stream>>>((ull_t*)hx);

    // sequential recurrence: h_t = relu(Z_t + h_{t-1} @ W_hh^T) -> clean trace + ring
    recurrence_kernel<<<64, 256, 0, stream>>>(Zb, W_hh, hbt, hx);

    // hiddens (fp32) = expand(hbt)
    expand_kernel<<<16384, 256, 0, stream>>>(hbt, hiddens, 4194304);

    // O = H @ W_out^T + b_out  [32768,256] fp32
    gemm_bt<0, 0, 0><<<512, 256, 0, stream>>>(hbt, Woutb, b_out, nullptr,
                                              outputs, nullptr, 32768, 256, 1024);
}

// Round 14
// 1399.790 us; speedup vs baseline: 1.2169x; 1.2169x over previous
//
#include <hip/hip_runtime.h>

typedef short bfx8 __attribute__((ext_vector_type(8)));   // 8 bf16 (bit pattern)
typedef float f32x4 __attribute__((ext_vector_type(4)));
typedef unsigned short ushort_t;
typedef unsigned int uint_t;
typedef unsigned long long ull_t;

#define SIGN4 0x8000800080008000ull
#define MASK4 0x7fff7fff7fff7fffull

__device__ inline ushort_t f2bf(float x) {
    union { float f; uint_t u; } v; v.f = x;
    uint_t r = v.u + 0x7fffu + ((v.u >> 16) & 1u);   // RNE
    return (ushort_t)(r >> 16);
}
__device__ inline float bf2f(ushort_t b) {
    union { uint_t u; float f; } v; v.u = ((uint_t)b) << 16;
    return v.f;
}

// async global->LDS, 16B per lane; lds dest = wave-uniform base + lane*16 (m97 pattern)
__device__ __forceinline__ void gload_lds16(const void* g, void* l) {
    __builtin_amdgcn_global_load_lds(
        (const __attribute__((address_space(1))) unsigned int*)g,
        (__attribute__((address_space(3))) unsigned int*)l, 16, 0, 0);
}

// ---------------- fp32 -> bf16 conversion (vectorized) ----------------
__global__ void f2bf_kernel(const float* __restrict__ in, ushort_t* __restrict__ out, int n4) {
    int i = blockIdx.x * 256 + threadIdx.x;
    if (i < n4) {
        float4 v = ((const float4*)in)[i];
        ushort4 o;
        o.x = f2bf(v.x); o.y = f2bf(v.y); o.z = f2bf(v.z); o.w = f2bf(v.w);
        ((ushort4*)out)[i] = o;
    }
}

// bf16 trace -> fp32 hiddens (8 elems/thread)
__global__ void expand_kernel(const ushort_t* __restrict__ hb, float* __restrict__ out, int n8) {
    int i = blockIdx.x * 256 + threadIdx.x;
    if (i < n8) {
        bfx8 v = ((const bfx8*)hb)[i];
        float4 lo, hi;
        lo.x = bf2f((ushort_t)v[0]); lo.y = bf2f((ushort_t)v[1]);
        lo.z = bf2f((ushort_t)v[2]); lo.w = bf2f((ushort_t)v[3]);
        hi.x = bf2f((ushort_t)v[4]); hi.y = bf2f((ushort_t)v[5]);
        hi.z = bf2f((ushort_t)v[6]); hi.w = bf2f((ushort_t)v[7]);
        ((float4*)out)[2 * i] = lo;
        ((float4*)out)[2 * i + 1] = hi;
    }
}

// ring init: every bf16 sign bit = 1 (never matches first-use parity 0)
__global__ void init_ring(ull_t* __restrict__ p) {
    p[blockIdx.x * 256 + threadIdx.x] = SIGN4;
}

// ---------------- bf16 GEMM (m97-style): C[M,N] = A[M,K] @ Bw[N,K]^T + bias ------------
// 128x128 tile, BK=64, linear LDS [128][64] (no pad: global_load_lds writes linearly),
// staging via global_load_lds dwordx4 (16B/lane). A 64-bf16 row = 128B = 8 chunks of
// 16B: row = c>>3, col = (c&7)*8 elems  (R13 bug: used c>>2/(c&3) -> half-staged rows).
#define BM 128
#define BN 128
#define BKK 64

template<int RELU, int OUT_BF16, int HAS_B2>
__global__ __launch_bounds__(256)
void gemm_bt(const ushort_t* __restrict__ A, const ushort_t* __restrict__ Bw,
             const float* __restrict__ bias1, const float* __restrict__ bias2,
             float* __restrict__ Cf, ushort_t* __restrict__ Cb,
             int M, int N, int K)
{
    __shared__ ushort_t As[BM][BKK];
    __shared__ ushort_t Bs[BN][BKK];
    const int tid = threadIdx.x;
    const int l = tid & 63;
    const int wv = tid >> 6;
    const int wm = wv >> 1, wn = wv & 1;
    const int nbm = M / BM;
    const int im = blockIdx.x % nbm;
    const int in = blockIdx.x / nbm;
    const int m0 = im * BM, n0 = in * BN;
    const int wbase = tid & ~63;           // wave-uniform lane-0 chunk index

    f32x4 acc[4][4];
#pragma unroll
    for (int i = 0; i < 4; i++)
#pragma unroll
        for (int j = 0; j < 4; j++) acc[i][j] = {0.f, 0.f, 0.f, 0.f};

    for (int k0 = 0; k0 < K; k0 += BKK) {
        // stage A,B tiles: 1024 chunks x 16B each; 4 calls/thread/tile
#pragma unroll
        for (int i = 0; i < 4; ++i) {
            int c = i * 256 + tid;                    // per-lane chunk
            int row = c >> 3, col = (c & 7) * 8;      // 8x16B chunks per 64-elem row
            int cbase = i * 256 + wbase;              // wave-uniform
            gload_lds16(&A[(size_t)(m0 + row) * K + k0 + col],
                        (char*)&As[0][0] + (size_t)cbase * 16);
        }
#pragma unroll
        for (int i = 0; i < 4; ++i) {
            int c = i * 256 + tid;
            int row = c >> 3, col = (c & 7) * 8;
            int cbase = i * 256 + wbase;
            gload_lds16(&Bw[(size_t)(n0 + row) * K + k0 + col],
                        (char*)&Bs[0][0] + (size_t)cbase * 16);
        }
        __syncthreads();   // compiler drains vmcnt (incl. global_load_lds) before barrier
#pragma unroll
        for (int kk = 0; kk < 2; ++kk) {
            bfx8 av[4], bv[4];
#pragma unroll
            for (int i = 0; i < 4; i++)
                av[i] = *(const bfx8*)&As[wm * 64 + i * 16 + (l & 15)][kk * 32 + (l >> 4) * 8];
#pragma unroll
            for (int i = 0; i < 4; i++)
                bv[i] = *(const bfx8*)&Bs[wn * 64 + i * 16 + (l & 15)][kk * 32 + (l >> 4) * 8];
#pragma unroll
            for (int i = 0; i < 4; i++)
#pragma unroll
                for (int j = 0; j < 4; j++)
                    acc[i][j] = __builtin_amdgcn_mfma_f32_16x16x32_bf16(av[i], bv[j], acc[i][j], 0, 0, 0);
        }
        __syncthreads();
    }

#pragma unroll
    for (int j = 0; j < 4; j++) {
        int n = n0 + wn * 64 + j * 16 + (l & 15);
        float bi = bias1[n] + (HAS_B2 ? bias2[n] : 0.0f);
#pragma unroll
        for (int i = 0; i < 4; i++) {
            int mbase = m0 + wm * 64 + i * 16 + (l >> 4) * 4;
#pragma unroll
            for (int r = 0; r < 4; r++) {
                float v = acc[i][j][r] + bi;
                if (RELU) v = fmaxf(v, 0.0f);
                size_t idx = (size_t)(mbase + r) * N + n;
                if (OUT_BF16) Cb[idx] = f2bf(v);
                else          Cf[idx] = v;
            }
        }
    }
}

// ---------------- persistent recurrence kernel (EXACT R11: parity tags, 2B pack) -------
// 64 WGs = 4 batch-groups (16 rows) x 16 j-slices (64 cols). Exchange via 256 KB ring
// hx[2][64][1024] (slot = t&1); bf16 sign bits carry parity (t>>1)&1 (ReLU => true sign
// always 0). Producer packs directly from epilogue registers (4x 2B agent stores); the
// per-16-bit parity check tolerates torn 8B chunks. Z prefetch BEFORE the poll (its
// vmcnt drain delays round-1's check to ~950cy post-pack == data-visible time; moving
// it later was R12's regression). Consumer-side coalesced trace store (one 2KB block
// per WG per step). DO NOT reorder the poll window.
#define T_STEPS 512

#define STEP(t, zc, zn, rd, wr)                                                         \
    do {                                                                                \
        const ull_t pb4 = (((t) >> 1) & 1) ? SIGN4 : 0ull;                              \
        const ushort_t pbu = (((t) >> 1) & 1) ? (ushort_t)0x8000u : (ushort_t)0;        \
        f32x4 a0 = {0.f,0.f,0.f,0.f}, a1 = {0.f,0.f,0.f,0.f};                           \
        f32x4 a2 = {0.f,0.f,0.f,0.f}, a3 = {0.f,0.f,0.f,0.f};                           \
        if ((t) > 0) {                                                                  \
            _Pragma("unroll") for (int k0 = 0; k0 < 32; k0 += 4) {                      \
                bfx8 h0 = *(const bfx8*)&rd[l & 15][(k0 + 0) * 32 + (l >> 4) * 8];      \
                bfx8 h1 = *(const bfx8*)&rd[l & 15][(k0 + 1) * 32 + (l >> 4) * 8];      \
                bfx8 h2 = *(const bfx8*)&rd[l & 15][(k0 + 2) * 32 + (l >> 4) * 8];      \
                bfx8 h3 = *(const bfx8*)&rd[l & 15][(k0 + 3) * 32 + (l >> 4) * 8];      \
                a0 = __builtin_amdgcn_mfma_f32_16x16x32_bf16(h0, wreg[k0 + 0], a0, 0, 0, 0); \
                a1 = __builtin_amdgcn_mfma_f32_16x16x32_bf16(h1, wreg[k0 + 1], a1, 0, 0, 0); \
                a2 = __builtin_amdgcn_mfma_f32_16x16x32_bf16(h2, wreg[k0 + 2], a2, 0, 0, 0); \
                a3 = __builtin_amdgcn_mfma_f32_16x16x32_bf16(h3, wreg[k0 + 3], a3, 0, 0, 0); \
            }                                                                           \
        }                                                                               \
        f32x4 acc = (a0 + a1) + (a2 + a3);                                              \
        ushort_t hv[4];                                                                 \
        _Pragma("unroll") for (int r = 0; r < 4; r++) {                                 \
            int br = (l >> 4) * 4 + r;                                                  \
            hv[r] = f2bf(fmaxf(zc[r] + acc[r], 0.f));                                   \
            /* direct 2B pack from registers: fire-and-forget, agent scope */           \
            __hip_atomic_store(                                                         \
                &hx[(size_t)((t) & 1) * 65536 + (size_t)(b0 + br) * 1024 + jcol],       \
                (ushort_t)(hv[r] | pbu), __ATOMIC_RELAXED, __HIP_MEMORY_SCOPE_AGENT);   \
        }                                                                               \
        if ((t) + 1 < T_STEPS) {                                                        \
            _Pragma("unroll") for (int r = 0; r < 4; r++) {   /* Z prefetch t+1 */      \
                int br = (l >> 4) * 4 + r;                                              \
                zn[r] = bf2f(__builtin_nontemporal_load(                                \
                    &Z[((size_t)((t) + 1) * 64 + b0 + br) * 1024 + jcol]));             \
            }                                                                           \
            /* batched poll rounds: 16 loads -> check all -> repeat */                  \
            const ull_t* src = (const ull_t*)(hx + (size_t)((t) & 1) * 65536            \
                                              + (size_t)b0 * 1024);                     \
            ull_t sv[16];                                                               \
            uint_t okm;                                                                 \
            do {                                                                        \
                _Pragma("unroll") for (int i2 = 0; i2 < 16; i2++)                       \
                    sv[i2] = __hip_atomic_load(src + i2 * 256 + tid, __ATOMIC_RELAXED,  \
                                               __HIP_MEMORY_SCOPE_AGENT);               \
                okm = 1u;                                                               \
                _Pragma("unroll") for (int i2 = 0; i2 < 16; i2++)                       \
                    okm &= (uint_t)((sv[i2] & SIGN4) == pb4);                           \
            } while (!okm);                                                             \
            /* consumer-side coalesced trace: this WG owns chunks [w*256, w*256+256) */ \
            __builtin_nontemporal_store(sv[w] & MASK4,                                  \
                (ull_t*)(hbt + (size_t)(t) * 65536 + (size_t)b0 * 1024)                 \
                    + (size_t)w * 256 + tid);                                           \
            _Pragma("unroll") for (int i2 = 0; i2 < 16; i2++)                           \
                *(ull_t*)&wr[i2][tid * 4] = sv[i2] & MASK4;                             \
            asm volatile("s_waitcnt lgkmcnt(0)" ::: "memory");                          \
            __builtin_amdgcn_s_barrier();                                               \
            __builtin_amdgcn_sched_barrier(0);                                          \
        } else {                                                                        \
            /* final step: trace from registers (once; 2B nontemporal) */               \
            _Pragma("unroll") for (int r = 0; r < 4; r++) {                             \
                int br = (l >> 4) * 4 + r;                                              \
                __builtin_nontemporal_store(hv[r],                                      \
                    &hbt[(size_t)(t) * 65536 + (size_t)(b0 + br) * 1024 + jcol]);       \
            }                                                                           \
        }                                                                               \
    } while (0)

__global__ __launch_bounds__(256, 1)
void recurrence_kernel(const ushort_t* __restrict__ Z,     // [T*64,1024] bf16
                       const float* __restrict__ W_hh,     // [1024,1024] fp32
                       ushort_t* __restrict__ hbt,         // [T*64,1024] bf16 clean trace
                       ushort_t* __restrict__ hx)          // [2*64,1024] bf16 parity ring
{
    alignas(16) __shared__ ushort_t Hs0[16][1048];   // double-buffered group-h staging
    alignas(16) __shared__ ushort_t Hs1[16][1048];

    const int tid = threadIdx.x;
    const int l = tid & 63;
    const int v = tid >> 6;                // wave 0..3
    const int g = blockIdx.x >> 4;         // batch group 0..3
    const int w = blockIdx.x & 15;         // j-slice 0..15
    const int b0 = g * 16;
    const int jcol = w * 64 + v * 16 + (l & 15);

    // one-time: W_hh slice -> registers (fp32 -> bf16), 128 VGPRs
    bfx8 wreg[32];
#pragma unroll
    for (int k0 = 0; k0 < 32; k0++) {
        const float* p = &W_hh[(size_t)jcol * 1024 + k0 * 32 + (l >> 4) * 8];
        float4 f0 = *(const float4*)p;
        float4 f1 = *(const float4*)(p + 4);
        bfx8 t;
        t[0] = (short)f2bf(f0.x); t[1] = (short)f2bf(f0.y);
        t[2] = (short)f2bf(f0.z); t[3] = (short)f2bf(f0.w);
        t[4] = (short)f2bf(f1.x); t[5] = (short)f2bf(f1.y);
        t[6] = (short)f2bf(f1.z); t[7] = (short)f2bf(f1.w);
        wreg[k0] = t;
    }

    // Z for t=0
    float zfA[4], zfB[4];
#pragma unroll
    for (int r = 0; r < 4; r++) {
        int br = (l >> 4) * 4 + r;
        zfA[r] = bf2f(__builtin_nontemporal_load(&Z[(size_t)(b0 + br) * 1024 + jcol]));
    }

    for (int t2 = 0; t2 < T_STEPS; t2 += 2) {
        STEP(t2,     zfA, zfB, Hs0, Hs1);
        STEP(t2 + 1, zfB, zfA, Hs1, Hs0);
    }
}

extern "C" void kernel_launch(void* const* d_in, const int* in_sizes, int n_in,
                              void* d_out, int out_size, void* d_ws, size_t ws_size,
                              hipStream_t stream) {
    const float* in_sig = (const float*)d_in[0];   // [512,64,256]
    const float* W_in  = (const float*)d_in[2];    // [1024,256]
    const float* b_in  = (const float*)d_in[3];
    const float* W_ih  = (const float*)d_in[4];    // [1024,1024]
    const float* b_ih  = (const float*)d_in[5];
    const float* W_hh  = (const float*)d_in[6];    // [1024,1024]
    const float* b_hh  = (const float*)d_in[7];
    const float* W_out = (const float*)d_in[8];    // [256,1024]
    const float* b_out = (const float*)d_in[9];

    char* ws = (char*)d_ws;
    const size_t MB = 1ull << 20;
    ushort_t* inb   = (ushort_t*)(ws + 0);          // 16 MB  [0,16)
    ushort_t* Winb  = (ushort_t*)(ws + 17 * MB);    // 0.5 MB
    ushort_t* Wihb  = (ushort_t*)(ws + 18 * MB);    // 2 MB
    ushort_t* Xb    = (ushort_t*)(ws + 21 * MB);    // 64 MB  [21,85)
    ushort_t* hbt   = (ushort_t*)(ws + 0);          // 64 MB  alias [0,64) — dead by then
    ushort_t* Woutb = (ushort_t*)(ws + 85 * MB);    // 0.5 MB
    ushort_t* Zb    = (ushort_t*)(ws + 86 * MB);    // 64 MB  [86,150)
    ushort_t* hx    = (ushort_t*)(ws + 150 * MB);   // 256 KB parity ring

    float* hiddens = (float*)d_out;                      // [512,64,1024]
    float* outputs = (float*)d_out + 33554432;           // [512,64,256]

    f2bf_kernel<<<8192, 256, 0, stream>>>(in_sig, inb, 2097152);
    f2bf_kernel<<<256, 256, 0, stream>>>(W_in, Winb, 65536);
    f2bf_kernel<<<1024, 256, 0, stream>>>(W_ih, Wihb, 262144);
    f2bf_kernel<<<256, 256, 0, stream>>>(W_out, Woutb, 65536);

    // X = relu(In @ W_in^T + b_in)  [32768,1024] bf16
    gemm_bt<1, 1, 0><<<2048, 256, 0, stream>>>(inb, Winb, b_in, nullptr,
                                               nullptr, Xb, 32768, 1024, 256);
    // Z = X @ W_ih^T + b_ih + b_hh  [32768,1024] bf16
    gemm_bt<0, 1, 1><<<2048, 256, 0, stream>>>(Xb, Wihb, b_ih, b_hh,
                                               nullptr, Zb, 32768, 1024, 1024);

    // ring -> sign=1 (blocks first-step poll until real data; replay-safe)
    init_ring<<<128, 256, 0, stream>>>((ull_t*)hx);

    // sequential recurrence: h_t = relu(Z_t + h_{t-1} @ W_hh^T) -> clean trace + ring
    recurrence_kernel<<<64, 256, 0, stream>>>(Zb, W_hh, hbt, hx);

    // hiddens (fp32) = expand(hbt)
    expand_kernel<<<16384, 256, 0, stream>>>(hbt, hiddens, 4194304);

    // O = H @ W_out^T + b_out  [32768,256] fp32
    gemm_bt<0, 0, 0><<<512, 256, 0, stream>>>(hbt, Woutb, b_out, nullptr,
                                              outputs, nullptr, 32768, 256, 1024);
}

// Round 15
// 1362.127 us; speedup vs baseline: 1.2506x; 1.0277x over previous
//
#include <hip/hip_runtime.h>

typedef short bfx8 __attribute__((ext_vector_type(8)));   // 8 bf16 (bit pattern)
typedef float f32x4 __attribute__((ext_vector_type(4)));
typedef unsigned short ushort_t;
typedef unsigned int uint_t;
typedef unsigned long long ull_t;

#define SIGN4 0x8000800080008000ull
#define MASK4 0x7fff7fff7fff7fffull

__device__ inline ushort_t f2bf(float x) {
    union { float f; uint_t u; } v; v.f = x;
    uint_t r = v.u + 0x7fffu + ((v.u >> 16) & 1u);   // RNE
    return (ushort_t)(r >> 16);
}
__device__ inline float bf2f(ushort_t b) {
    union { uint_t u; float f; } v; v.u = ((uint_t)b) << 16;
    return v.f;
}

// ---------------- fused prep: 4x f2bf conversions + ring init (one launch) ------------
__global__ __launch_bounds__(256)
void prep_kernel(const float* __restrict__ in_sig, ushort_t* __restrict__ inb,
                 const float* __restrict__ W_in,  ushort_t* __restrict__ Winb,
                 const float* __restrict__ W_ih,  ushort_t* __restrict__ Wihb,
                 const float* __restrict__ W_out, ushort_t* __restrict__ Woutb,
                 ull_t* __restrict__ ring)
{
    const int bid = blockIdx.x, tid = threadIdx.x;
    const float* src; ushort_t* dst; int i;
    if (bid < 8192)      { src = in_sig; dst = inb;  i = bid * 256 + tid; }
    else if (bid < 8448) { src = W_in;  dst = Winb;  i = (bid - 8192) * 256 + tid; }
    else if (bid < 9472) { src = W_ih;  dst = Wihb;  i = (bid - 8448) * 256 + tid; }
    else if (bid < 9728) { src = W_out; dst = Woutb; i = (bid - 9472) * 256 + tid; }
    else {   // ring init: every bf16 sign bit = 1 (never matches first-use parity 0)
        ring[(size_t)(bid - 9728) * 256 + tid] = SIGN4;
        return;
    }
    float4 v = ((const float4*)src)[i];
    ushort4 o;
    o.x = f2bf(v.x); o.y = f2bf(v.y); o.z = f2bf(v.z); o.w = f2bf(v.w);
    ((ushort4*)dst)[i] = o;
}

// ---------------- generic bf16 GEMM body (R11-proven: padded LDS, VGPR staging) --------
#define BM 128
#define BN 128
#define BKK 64
#define LDT 88   // padded LDS row stride in bf16 elems

template<int RELU, int OUT_BF16, int HAS_B2>
__device__ __forceinline__
void gemm_body(const ushort_t* __restrict__ A, const ushort_t* __restrict__ Bw,
               const float* __restrict__ bias1, const float* __restrict__ bias2,
               float* __restrict__ Cf, ushort_t* __restrict__ Cb,
               int M, int N, int K, int bid,
               ushort_t (*As)[LDT], ushort_t (*Bs)[LDT])
{
    const int tid = threadIdx.x;
    const int l = tid & 63;
    const int wv = tid >> 6;
    const int wm = wv >> 1, wn = wv & 1;
    const int nbm = M / BM;
    const int im = bid % nbm;
    const int in = bid / nbm;
    const int m0 = im * BM, n0 = in * BN;

    f32x4 acc[4][4];
#pragma unroll
    for (int i = 0; i < 4; i++)
#pragma unroll
        for (int j = 0; j < 4; j++) acc[i][j] = {0.f, 0.f, 0.f, 0.f};

    for (int k0 = 0; k0 < K; k0 += BKK) {
#pragma unroll
        for (int i = 0; i < 4; ++i) {
            int c = i * 256 + tid;
            int row = c >> 3, cb = c & 7;
            *(bfx8*)&As[row][cb * 8] = *(const bfx8*)&A[(size_t)(m0 + row) * K + k0 + cb * 8];
        }
#pragma unroll
        for (int i = 0; i < 4; ++i) {
            int c = i * 256 + tid;
            int row = c >> 3, cb = c & 7;
            *(bfx8*)&Bs[row][cb * 8] = *(const bfx8*)&Bw[(size_t)(n0 + row) * K + k0 + cb * 8];
        }
        __syncthreads();
#pragma unroll
        for (int kk = 0; kk < 2; ++kk) {
            bfx8 av[4], bv[4];
#pragma unroll
            for (int i = 0; i < 4; i++)
                av[i] = *(const bfx8*)&As[wm * 64 + i * 16 + (l & 15)][kk * 32 + (l >> 4) * 8];
#pragma unroll
            for (int i = 0; i < 4; i++)
                bv[i] = *(const bfx8*)&Bs[wn * 64 + i * 16 + (l & 15)][kk * 32 + (l >> 4) * 8];
#pragma unroll
            for (int i = 0; i < 4; i++)
#pragma unroll
                for (int j = 0; j < 4; j++)
                    acc[i][j] = __builtin_amdgcn_mfma_f32_16x16x32_bf16(av[i], bv[j], acc[i][j], 0, 0, 0);
        }
        __syncthreads();
    }

#pragma unroll
    for (int j = 0; j < 4; j++) {
        int n = n0 + wn * 64 + j * 16 + (l & 15);
        float bi = bias1[n] + (HAS_B2 ? bias2[n] : 0.0f);
#pragma unroll
        for (int i = 0; i < 4; i++) {
            int mbase = m0 + wm * 64 + i * 16 + (l >> 4) * 4;
#pragma unroll
            for (int r = 0; r < 4; r++) {
                float v = acc[i][j][r] + bi;
                if (RELU) v = fmaxf(v, 0.0f);
                size_t idx = (size_t)(mbase + r) * N + n;
                if (OUT_BF16) Cb[idx] = f2bf(v);
                else          Cf[idx] = v;
            }
        }
    }
}

template<int RELU, int OUT_BF16, int HAS_B2>
__global__ __launch_bounds__(256)
void gemm_bt(const ushort_t* __restrict__ A, const ushort_t* __restrict__ Bw,
             const float* __restrict__ bias1, const float* __restrict__ bias2,
             float* __restrict__ Cf, ushort_t* __restrict__ Cb,
             int M, int N, int K)
{
    __shared__ ushort_t As[BM][LDT];
    __shared__ ushort_t Bs[BN][LDT];
    gemm_body<RELU, OUT_BF16, HAS_B2>(A, Bw, bias1, bias2, Cf, Cb, M, N, K,
                                      blockIdx.x, As, Bs);
}

// ---------------- fused tail: out-GEMM (blocks 0..511) + hiddens expand (rest) ---------
__global__ __launch_bounds__(256)
void tail_kernel(const ushort_t* __restrict__ hbt, const ushort_t* __restrict__ Woutb,
                 const float* __restrict__ b_out, float* __restrict__ outputs,
                 float* __restrict__ hiddens)
{
    __shared__ ushort_t As[BM][LDT];
    __shared__ ushort_t Bs[BN][LDT];
    const int bid = blockIdx.x;
    if (bid < 512) {
        // O = H @ W_out^T + b_out   [32768,256] fp32
        gemm_body<0, 0, 0>(hbt, Woutb, b_out, nullptr, outputs, nullptr,
                           32768, 256, 1024, bid, As, Bs);
    } else {
        // hiddens (fp32) = expand(hbt), 8 elems/thread
        int i = (bid - 512) * 256 + threadIdx.x;
        bfx8 v = ((const bfx8*)hbt)[i];
        float4 lo, hi;
        lo.x = bf2f((ushort_t)v[0]); lo.y = bf2f((ushort_t)v[1]);
        lo.z = bf2f((ushort_t)v[2]); lo.w = bf2f((ushort_t)v[3]);
        hi.x = bf2f((ushort_t)v[4]); hi.y = bf2f((ushort_t)v[5]);
        hi.z = bf2f((ushort_t)v[6]); hi.w = bf2f((ushort_t)v[7]);
        ((float4*)hiddens)[2 * i] = lo;
        ((float4*)hiddens)[2 * i + 1] = hi;
    }
}

// ---------------- persistent recurrence kernel (EXACT R11: parity tags, 2B pack) -------
// 64 WGs = 4 batch-groups (16 rows) x 16 j-slices (64 cols). Exchange via 256 KB ring
// hx[2][64][1024] (slot = t&1); bf16 sign bits carry parity (t>>1)&1 (ReLU => true sign
// always 0). Producer packs directly from epilogue registers (4x 2B agent stores); the
// per-16-bit parity check tolerates torn 8B chunks. Z prefetch BEFORE the poll (its
// vmcnt drain delays round-1's check to ~950cy post-pack == data-visible time; moving
// it later was R12's regression). Consumer-side coalesced trace store (one 2KB block
// per WG per step). DO NOT reorder the poll window.
#define T_STEPS 512

#define STEP(t, zc, zn, rd, wr)                                                         \
    do {                                                                                \
        const ull_t pb4 = (((t) >> 1) & 1) ? SIGN4 : 0ull;                              \
        const ushort_t pbu = (((t) >> 1) & 1) ? (ushort_t)0x8000u : (ushort_t)0;        \
        f32x4 a0 = {0.f,0.f,0.f,0.f}, a1 = {0.f,0.f,0.f,0.f};                           \
        f32x4 a2 = {0.f,0.f,0.f,0.f}, a3 = {0.f,0.f,0.f,0.f};                           \
        if ((t) > 0) {                                                                  \
            _Pragma("unroll") for (int k0 = 0; k0 < 32; k0 += 4) {                      \
                bfx8 h0 = *(const bfx8*)&rd[l & 15][(k0 + 0) * 32 + (l >> 4) * 8];      \
                bfx8 h1 = *(const bfx8*)&rd[l & 15][(k0 + 1) * 32 + (l >> 4) * 8];      \
                bfx8 h2 = *(const bfx8*)&rd[l & 15][(k0 + 2) * 32 + (l >> 4) * 8];      \
                bfx8 h3 = *(const bfx8*)&rd[l & 15][(k0 + 3) * 32 + (l >> 4) * 8];      \
                a0 = __builtin_amdgcn_mfma_f32_16x16x32_bf16(h0, wreg[k0 + 0], a0, 0, 0, 0); \
                a1 = __builtin_amdgcn_mfma_f32_16x16x32_bf16(h1, wreg[k0 + 1], a1, 0, 0, 0); \
                a2 = __builtin_amdgcn_mfma_f32_16x16x32_bf16(h2, wreg[k0 + 2], a2, 0, 0, 0); \
                a3 = __builtin_amdgcn_mfma_f32_16x16x32_bf16(h3, wreg[k0 + 3], a3, 0, 0, 0); \
            }                                                                           \
        }                                                                               \
        f32x4 acc = (a0 + a1) + (a2 + a3);                                              \
        ushort_t hv[4];                                                                 \
        _Pragma("unroll") for (int r = 0; r < 4; r++) {                                 \
            int br = (l >> 4) * 4 + r;                                                  \
            hv[r] = f2bf(fmaxf(zc[r] + acc[r], 0.f));                                   \
            /* direct 2B pack from registers: fire-and-forget, agent scope */           \
            __hip_atomic_store(                                                         \
                &hx[(size_t)((t) & 1) * 65536 + (size_t)(b0 + br) * 1024 + jcol],       \
                (ushort_t)(hv[r] | pbu), __ATOMIC_RELAXED, __HIP_MEMORY_SCOPE_AGENT);   \
        }                                                                               \
        if ((t) + 1 < T_STEPS) {                                                        \
            _Pragma("unroll") for (int r = 0; r < 4; r++) {   /* Z prefetch t+1 */      \
                int br = (l >> 4) * 4 + r;                                              \
                zn[r] = bf2f(__builtin_nontemporal_load(                                \
                    &Z[((size_t)((t) + 1) * 64 + b0 + br) * 1024 + jcol]));             \
            }                                                                           \
            /* batched poll rounds: 16 loads -> check all -> repeat */                  \
            const ull_t* src = (const ull_t*)(hx + (size_t)((t) & 1) * 65536            \
                                              + (size_t)b0 * 1024);                     \
            ull_t sv[16];                                                               \
            uint_t okm;                                                                 \
            do {                                                                        \
                _Pragma("unroll") for (int i2 = 0; i2 < 16; i2++)                       \
                    sv[i2] = __hip_atomic_load(src + i2 * 256 + tid, __ATOMIC_RELAXED,  \
                                               __HIP_MEMORY_SCOPE_AGENT);               \
                okm = 1u;                                                               \
                _Pragma("unroll") for (int i2 = 0; i2 < 16; i2++)                       \
                    okm &= (uint_t)((sv[i2] & SIGN4) == pb4);                           \
            } while (!okm);                                                             \
            /* consumer-side coalesced trace: this WG owns chunks [w*256, w*256+256) */ \
            __builtin_nontemporal_store(sv[w] & MASK4,                                  \
                (ull_t*)(hbt + (size_t)(t) * 65536 + (size_t)b0 * 1024)                 \
                    + (size_t)w * 256 + tid);                                           \
            _Pragma("unroll") for (int i2 = 0; i2 < 16; i2++)                           \
                *(ull_t*)&wr[i2][tid * 4] = sv[i2] & MASK4;                             \
            asm volatile("s_waitcnt lgkmcnt(0)" ::: "memory");                          \
            __builtin_amdgcn_s_barrier();                                               \
            __builtin_amdgcn_sched_barrier(0);                                          \
        } else {                                                                        \
            /* final step: trace from registers (once; 2B nontemporal) */               \
            _Pragma("unroll") for (int r = 0; r < 4; r++) {                             \
                int br = (l >> 4) * 4 + r;                                              \
                __builtin_nontemporal_store(hv[r],                                      \
                    &hbt[(size_t)(t) * 65536 + (size_t)(b0 + br) * 1024 + jcol]);       \
            }                                                                           \
        }                                                                               \
    } while (0)

__global__ __launch_bounds__(256, 1)
void recurrence_kernel(const ushort_t* __restrict__ Z,     // [T*64,1024] bf16
                       const float* __restrict__ W_hh,     // [1024,1024] fp32
                       ushort_t* __restrict__ hbt,         // [T*64,1024] bf16 clean trace
                       ushort_t* __restrict__ hx)          // [2*64,1024] bf16 parity ring
{
    alignas(16) __shared__ ushort_t Hs0[16][1048];   // double-buffered group-h staging
    alignas(16) __shared__ ushort_t Hs1[16][1048];

    const int tid = threadIdx.x;
    const int l = tid & 63;
    const int v = tid >> 6;                // wave 0..3
    const int g = blockIdx.x >> 4;         // batch group 0..3
    const int w = blockIdx.x & 15;         // j-slice 0..15
    const int b0 = g * 16;
    const int jcol = w * 64 + v * 16 + (l & 15);

    // one-time: W_hh slice -> registers (fp32 -> bf16), 128 VGPRs
    bfx8 wreg[32];
#pragma unroll
    for (int k0 = 0; k0 < 32; k0++) {
        const float* p = &W_hh[(size_t)jcol * 1024 + k0 * 32 + (l >> 4) * 8];
        float4 f0 = *(const float4*)p;
        float4 f1 = *(const float4*)(p + 4);
        bfx8 t;
        t[0] = (short)f2bf(f0.x); t[1] = (short)f2bf(f0.y);
        t[2] = (short)f2bf(f0.z); t[3] = (short)f2bf(f0.w);
        t[4] = (short)f2bf(f1.x); t[5] = (short)f2bf(f1.y);
        t[6] = (short)f2bf(f1.z); t[7] = (short)f2bf(f1.w);
        wreg[k0] = t;
    }

    // Z for t=0
    float zfA[4], zfB[4];
#pragma unroll
    for (int r = 0; r < 4; r++) {
        int br = (l >> 4) * 4 + r;
        zfA[r] = bf2f(__builtin_nontemporal_load(&Z[(size_t)(b0 + br) * 1024 + jcol]));
    }

    for (int t2 = 0; t2 < T_STEPS; t2 += 2) {
        STEP(t2,     zfA, zfB, Hs0, Hs1);
        STEP(t2 + 1, zfB, zfA, Hs1, Hs0);
    }
}

extern "C" void kernel_launch(void* const* d_in, const int* in_sizes, int n_in,
                              void* d_out, int out_size, void* d_ws, size_t ws_size,
                              hipStream_t stream) {
    const float* in_sig = (const float*)d_in[0];   // [512,64,256]
    const float* W_in  = (const float*)d_in[2];    // [1024,256]
    const float* b_in  = (const float*)d_in[3];
    const float* W_ih  = (const float*)d_in[4];    // [1024,1024]
    const float* b_ih  = (const float*)d_in[5];
    const float* W_hh  = (const float*)d_in[6];    // [1024,1024]
    const float* b_hh  = (const float*)d_in[7];
    const float* W_out = (const float*)d_in[8];    // [256,1024]
    const float* b_out = (const float*)d_in[9];

    char* ws = (char*)d_ws;
    const size_t MB = 1ull << 20;
    ushort_t* inb   = (ushort_t*)(ws + 0);          // 16 MB  [0,16)
    ushort_t* Winb  = (ushort_t*)(ws + 17 * MB);    // 0.5 MB
    ushort_t* Wihb  = (ushort_t*)(ws + 18 * MB);    // 2 MB
    ushort_t* Xb    = (ushort_t*)(ws + 21 * MB);    // 64 MB  [21,85)
    ushort_t* hbt   = (ushort_t*)(ws + 0);          // 64 MB  alias [0,64) — dead by then
    ushort_t* Woutb = (ushort_t*)(ws + 85 * MB);    // 0.5 MB
    ushort_t* Zb    = (ushort_t*)(ws + 86 * MB);    // 64 MB  [86,150)
    ushort_t* hx    = (ushort_t*)(ws + 150 * MB);   // 256 KB parity ring

    float* hiddens = (float*)d_out;                      // [512,64,1024]
    float* outputs = (float*)d_out + 33554432;           // [512,64,256]

    // fused conversions + ring init (9856 blocks: 8192 in + 256 Win + 1024 Wih + 256 Wout + 128 ring)
    prep_kernel<<<9856, 256, 0, stream>>>(in_sig, inb, W_in, Winb, W_ih, Wihb,
                                          W_out, Woutb, (ull_t*)hx);

    // X = relu(In @ W_in^T + b_in)  [32768,1024] bf16
    gemm_bt<1, 1, 0><<<2048, 256, 0, stream>>>(inb, Winb, b_in, nullptr,
                                               nullptr, Xb, 32768, 1024, 256);
    // Z = X @ W_ih^T + b_ih + b_hh  [32768,1024] bf16
    gemm_bt<0, 1, 1><<<2048, 256, 0, stream>>>(Xb, Wihb, b_ih, b_hh,
                                               nullptr, Zb, 32768, 1024, 1024);

    // sequential recurrence: h_t = relu(Z_t + h_{t-1} @ W_hh^T) -> clean trace + ring
    recurrence_kernel<<<64, 256, 0, stream>>>(Zb, W_hh, hbt, hx);

    // fused tail: O = H @ W_out^T + b_out (512 blocks) + hiddens = expand(hbt) (16384)
    tail_kernel<<<16896, 256, 0, stream>>>(hbt, Woutb, b_out, outputs, hiddens);
}